// Round 12
// baseline (609.229 us; speedup 1.0000x reference)
//
#include <hip/hip_runtime.h>
#include <hip/hip_bf16.h>
#include <cstdint>

// Problem constants (fixed by the reference)
constexpr int  KDIM  = 4096;    // D_IN
constexpr int  NDIM  = 4096;    // D_OUT
constexpr long MDIM  = 16384;   // B*S
constexpr int  RANK_ = 16;
constexpr float SCALE_ = 2.0f;  // alpha/rank

constexpr int BK = 64;
constexpr int NT = KDIM / BK;   // 64 K-tiles

using bf16x8 = __attribute__((ext_vector_type(8))) short;
using f32x4  = __attribute__((ext_vector_type(4))) float;

__device__ __forceinline__ void gload_lds16(const void* g, void* l) {
  __builtin_amdgcn_global_load_lds(
      (const __attribute__((address_space(1))) void*)g,
      (__attribute__((address_space(3))) void*)l, 16, 0, 0);
}

__device__ __forceinline__ unsigned short f2bf(float f) {
  union { float f; unsigned u; } v; v.f = f;
  unsigned r = v.u + 0x7FFFu + ((v.u >> 16) & 1u);
  return (unsigned short)(r >> 16);
}

// immediate-offset LDS fragment read (compiler folds OFF into ds_read offset:)
#define LDF(P, OFF) (*reinterpret_cast<const bf16x8*>((P) + (OFF)))

// ---------------------------------------------------------------------------
// Kernel 1: W' = bf16( W + SCALE * lora_B @ lora_A )   [NDIM][KDIM]
// ---------------------------------------------------------------------------
__global__ __launch_bounds__(256) void prep_w_kernel(
    const float* __restrict__ W, const float* __restrict__ lA,
    const float* __restrict__ lB, unsigned short* __restrict__ Wp) {
  const long total8 = (long)NDIM * KDIM / 8;
  for (long t = blockIdx.x * (long)blockDim.x + threadIdx.x; t < total8;
       t += (long)gridDim.x * blockDim.x) {
    const int o  = (int)(t / (KDIM / 8));
    const int d8 = (int)(t % (KDIM / 8)) * 8;
    const float4* w4 = reinterpret_cast<const float4*>(W + (size_t)o * KDIM + d8);
    float4 w0 = w4[0], w1 = w4[1];
    float acc[8] = {w0.x, w0.y, w0.z, w0.w, w1.x, w1.y, w1.z, w1.w};
#pragma unroll
    for (int r = 0; r < RANK_; ++r) {
      const float br = SCALE_ * lB[o * RANK_ + r];
      const float4* a4 = reinterpret_cast<const float4*>(lA + (size_t)r * KDIM + d8);
      float4 a0 = a4[0], a1 = a4[1];
      acc[0] += br * a0.x; acc[1] += br * a0.y; acc[2] += br * a0.z; acc[3] += br * a0.w;
      acc[4] += br * a1.x; acc[5] += br * a1.y; acc[6] += br * a1.z; acc[7] += br * a1.w;
    }
    uint4 o4;
    o4.x = (unsigned)f2bf(acc[0]) | ((unsigned)f2bf(acc[1]) << 16);
    o4.y = (unsigned)f2bf(acc[2]) | ((unsigned)f2bf(acc[3]) << 16);
    o4.z = (unsigned)f2bf(acc[4]) | ((unsigned)f2bf(acc[5]) << 16);
    o4.w = (unsigned)f2bf(acc[6]) | ((unsigned)f2bf(acc[7]) << 16);
    *reinterpret_cast<uint4*>(Wp + t * 8) = o4;
  }
}

// ---------------------------------------------------------------------------
// Kernel 2: xb = bf16(x)   [MDIM][KDIM]
// ---------------------------------------------------------------------------
__global__ __launch_bounds__(256) void conv_x_kernel(
    const float* __restrict__ x, unsigned short* __restrict__ xb) {
  const long total8 = MDIM * KDIM / 8;
  for (long t = blockIdx.x * (long)blockDim.x + threadIdx.x; t < total8;
       t += (long)gridDim.x * blockDim.x) {
    const float4* p = reinterpret_cast<const float4*>(x + t * 8);
    float4 a = p[0], b = p[1];
    uint4 o4;
    o4.x = (unsigned)f2bf(a.x) | ((unsigned)f2bf(a.y) << 16);
    o4.y = (unsigned)f2bf(a.z) | ((unsigned)f2bf(a.w) << 16);
    o4.z = (unsigned)f2bf(b.x) | ((unsigned)f2bf(b.y) << 16);
    o4.w = (unsigned)f2bf(b.z) | ((unsigned)f2bf(b.w) << 16);
    *reinterpret_cast<uint4*>(xb + t * 8) = o4;
  }
}

// ---------------------------------------------------------------------------
// Kernel 3: R10 structure with EARLY-ISSUE staging (wait schedule unchanged).
//   Region map (R11 lesson): wave wm reads ALL its x fragments from region
//   A{wm} -> the P4 boundary reads touch BOTH A0 and A1 of tile t+1, so
//   vmcnt(4)@P4 (retiring all of tile t+1) is the minimum legal wait.
//   To cover HBM latency we ISSUE EARLIER instead:
//     P1(t): stage A0(t+1)+A1(t+1)  [age at P4 wait: 3 phases ~750cyc]
//     P3(t): stage B0(t+2)+B1(t+2)  [age at wait: 5/4 phases]
//     P4(t): vmcnt(4) retires exactly B(t+1)+A(t+1); leaves B(t+2) in flight
//   FIFO invariant entering each P1: 4 loads outstanding [B halves of t+1].
//   Write-slot safety: A(t+1)@P1(t) vs last A(t-1) read @P2(t-1): 2 barriers;
//   B(t+2)@P3(t) vs last B(t) read @P1(t): 2 barriers. Audited.
//   Phases: P1 Q0 (xlo prev-P4, wlo/whi read here); P2 Q1 (+xhi reads);
//           P3 Q2; P4 vmcnt+bar, boundary xlo(t+1), Q3.
// ---------------------------------------------------------------------------
__global__ __launch_bounds__(512, 2) void gemm256_kernel(
    const unsigned short* __restrict__ A,   // [MDIM][KDIM] bf16 bits (x)
    const unsigned short* __restrict__ Bm,  // [NDIM][KDIM] bf16 bits (W')
    const float* __restrict__ bias,
    float* __restrict__ C) {
  __shared__ __align__(16) unsigned char lds[131072];

  const int tid  = threadIdx.x;
  const int wave = tid >> 6, lane = tid & 63;
  const int wm = wave >> 2, wn = wave & 3;       // 2 x 4 wave grid
  const int r16 = lane & 15, hi = lane >> 4;
  const int swz5 = ((r16 >> 3) & 1) << 5;        // verified-0-conflict swizzle
  const int lrB = (wn & 1) * 64;

  // XCD-aware bijective blockIdx swizzle, R4 orientation (verified lower fetch)
  const int orig = blockIdx.x;
  const int bid  = (orig & 7) * 128 + (orig >> 3);
  const int bcol = (bid & 15) * 256;             // N-tile
  const int brow = (bid >> 4) * 256;             // M-tile

  // staging geometry (verified R2): linear LDS dest + inverse-swizzled source
  const int st_row = wave * 16 + (lane >> 2);                     // 0..127
  const int st_col = ((lane & 3) * 8) ^ (((lane >> 5) & 1) << 4); // elem [0,32)
  const unsigned short* Asrc = A  + (size_t)(brow + st_row) * KDIM + st_col;
  const unsigned short* Bsrc = Bm + (size_t)(bcol + st_row) * KDIM + st_col;

  // stage half-tile s (0=B0,1=B1,2=A0,3=A1) of K-tile tau into buffer `base`
  auto stageHalf = [&](unsigned char* base, int s, int tau) {
    const unsigned short* g = (s >= 2 ? Asrc + (size_t)(s - 2) * 128 * KDIM
                                      : Bsrc + (size_t)s * 128 * KDIM) + tau * BK;
    unsigned char* d = base + (wave << 10) + s * 16384;
    gload_lds16(g,      d);            // kk0
    gload_lds16(g + 32, d + 8192);     // kk1
  };

  // per-lane ds-read base pointers; every fragment read = base + const offset:
  //   A frag (row m*16+r16, kk):      pA + m*1024 + kk*8192      (m 0..7)
  //   B frag (row lrB+n*16+r16, kk):  pB + n*1024 + kk*8192      (n 0..3)
  const int laneoff = r16 * 64 + ((hi * 16) ^ swz5);
  const unsigned char* pA0 = lds + (2 + wm) * 16384 + laneoff;
  const unsigned char* pB0 = lds + (wn >> 1) * 16384 + lrB * 64 + laneoff;
  const unsigned char* pA1 = pA0 + 65536;
  const unsigned char* pB1 = pB0 + 65536;

  f32x4 acc[8][4];
#pragma unroll
  for (int m = 0; m < 8; ++m)
#pragma unroll
    for (int n = 0; n < 4; ++n) acc[m][n] = (f32x4){0.f, 0.f, 0.f, 0.f};

  unsigned char* const buf0 = lds;
  unsigned char* const buf1 = lds + 65536;

  // prologue: tile0 full (buf0) + tile1 B0,B1 (buf1); vmcnt(4) retires tile0
  // (8 oldest loads), leaves B(1) in flight = steady-state invariant.
  stageHalf(buf0, 0, 0); stageHalf(buf0, 1, 0);
  stageHalf(buf0, 2, 0); stageHalf(buf0, 3, 0);
  stageHalf(buf1, 0, 1); stageHalf(buf1, 1, 1);
  asm volatile("s_waitcnt vmcnt(4)" ::: "memory");
  __builtin_amdgcn_s_barrier();

  bf16x8 xlo[4][2], xhi[4][2], wlo[2][2], whi[2][2];
  // boundary pre-read for tile 0: xlo (both kk) from buf0
#pragma unroll
  for (int m = 0; m < 4; ++m) {
    xlo[m][0] = LDF(pA0, m * 1024);
    xlo[m][1] = LDF(pA0, m * 1024 + 8192);
  }

  // One K-tile. CB/NB = cur/next staging buffer; PA/PB = cur read bases;
  // PAN = next A read base; t = tile index.
#define KTILE(CB, NB, PA, PB, PAN, t)                                          \
  {                                                                            \
    /* P1: read wlo+whi(t) (8); stage A0+A1(t+1); Q0 (xlo from prev P4) */     \
    _Pragma("unroll")                                                          \
    for (int n = 0; n < 2; ++n) {                                              \
      wlo[n][0] = LDF(PB, n * 1024);                                           \
      wlo[n][1] = LDF(PB, n * 1024 + 8192);                                    \
    }                                                                          \
    _Pragma("unroll")                                                          \
    for (int n = 0; n < 2; ++n) {                                              \
      whi[n][0] = LDF(PB, (n + 2) * 1024);                                     \
      whi[n][1] = LDF(PB, (n + 2) * 1024 + 8192);                              \
    }                                                                          \
    if ((t) + 1 < NT) { stageHalf((NB), 2, (t) + 1);                           \
                        stageHalf((NB), 3, (t) + 1); }                         \
    __builtin_amdgcn_s_setprio(1);                                             \
    _Pragma("unroll")                                                          \
    for (int kk = 0; kk < 2; ++kk)                                             \
      _Pragma("unroll")                                                        \
      for (int m = 0; m < 4; ++m)                                              \
        _Pragma("unroll")                                                      \
        for (int n = 0; n < 2; ++n)                                            \
          acc[m][n] = __builtin_amdgcn_mfma_f32_16x16x32_bf16(                 \
              wlo[n][kk], xlo[m][kk], acc[m][n], 0, 0, 0);                     \
    __builtin_amdgcn_s_setprio(0);                                             \
    __builtin_amdgcn_s_barrier();                                              \
    /* P2: read xhi(t) (8); Q1 (whi read P1); bar */                           \
    _Pragma("unroll")                                                          \
    for (int m = 0; m < 4; ++m) {                                              \
      xhi[m][0] = LDF(PA, (m + 4) * 1024);                                     \
      xhi[m][1] = LDF(PA, (m + 4) * 1024 + 8192);                              \
    }                                                                          \
    __builtin_amdgcn_s_setprio(1);                                             \
    _Pragma("unroll")                                                          \
    for (int kk = 0; kk < 2; ++kk)                                             \
      _Pragma("unroll")                                                        \
      for (int m = 0; m < 4; ++m)                                              \
        _Pragma("unroll")                                                      \
        for (int n = 0; n < 2; ++n)                                            \
          acc[m][n + 2] = __builtin_amdgcn_mfma_f32_16x16x32_bf16(             \
              whi[n][kk], xlo[m][kk], acc[m][n + 2], 0, 0, 0);                 \
    __builtin_amdgcn_s_setprio(0);                                             \
    __builtin_amdgcn_s_barrier();                                              \
    /* P3: no reads; stage B0+B1(t+2) into CB; Q2 (xhi read P2); bar */        \
    if ((t) + 2 < NT) { stageHalf((CB), 0, (t) + 2);                           \
                        stageHalf((CB), 1, (t) + 2); }                         \
    __builtin_amdgcn_s_setprio(1);                                             \
    _Pragma("unroll")                                                          \
    for (int kk = 0; kk < 2; ++kk)                                             \
      _Pragma("unroll")                                                        \
      for (int m = 0; m < 4; ++m)                                              \
        _Pragma("unroll")                                                      \
        for (int n = 0; n < 2; ++n)                                            \
          acc[m + 4][n + 2] = __builtin_amdgcn_mfma_f32_16x16x32_bf16(         \
              whi[n][kk], xhi[m][kk], acc[m + 4][n + 2], 0, 0, 0);             \
    __builtin_amdgcn_s_setprio(0);                                             \
    __builtin_amdgcn_s_barrier();                                              \
    /* P4: vmcnt(4) -> all of t+1 resident (A ages 3 phases), B(t+2) in        \
       flight; bar; boundary read xlo(t+1) (8) overlaps Q3 */                  \
    if ((t) < NT - 2)       asm volatile("s_waitcnt vmcnt(4)" ::: "memory");   \
    else if ((t) == NT - 2) asm volatile("s_waitcnt vmcnt(0)" ::: "memory");   \
    __builtin_amdgcn_s_barrier();                                              \
    if ((t) + 1 < NT) {                                                        \
      _Pragma("unroll")                                                        \
      for (int m = 0; m < 4; ++m) {                                            \
        xlo[m][0] = LDF(PAN, m * 1024);                                        \
        xlo[m][1] = LDF(PAN, m * 1024 + 8192);                                 \
      }                                                                        \
    }                                                                          \
    __builtin_amdgcn_s_setprio(1);                                             \
    _Pragma("unroll")                                                          \
    for (int kk = 0; kk < 2; ++kk)                                             \
      _Pragma("unroll")                                                        \
      for (int m = 0; m < 4; ++m)                                              \
        _Pragma("unroll")                                                      \
        for (int n = 0; n < 2; ++n)                                            \
          acc[m + 4][n] = __builtin_amdgcn_mfma_f32_16x16x32_bf16(             \
              wlo[n][kk], xhi[m][kk], acc[m + 4][n], 0, 0, 0);                 \
    __builtin_amdgcn_s_setprio(0);                                             \
  }

  for (int tt = 0; tt < NT; tt += 2) {
    KTILE(buf0, buf1, pA0, pB0, pA1, tt);
    KTILE(buf1, buf0, pA1, pB1, pA0, tt + 1);
  }
#undef KTILE

  // epilogue (verified R3/R4): swapped C/D layout -> lane holds 4 consecutive
  // C columns: Crow = brow + wm*128 + m*16 + (lane&15),
  //            Ccol = bcol + wn*64 + n*16 + hi*4 + j  -> dwordx4 stores
#pragma unroll
  for (int n = 0; n < 4; ++n) {
    const int colb = bcol + wn * 64 + n * 16 + hi * 4;
    const f32x4 bv = *reinterpret_cast<const f32x4*>(&bias[colb]);
#pragma unroll
    for (int m = 0; m < 8; ++m) {
      const size_t row = (size_t)brow + wm * 128 + m * 16 + r16;
      f32x4 v = acc[m][n] + bv;
      *reinterpret_cast<f32x4*>(&C[row * NDIM + colb]) = v;
    }
  }
}

// ---------------------------------------------------------------------------
extern "C" void kernel_launch(void* const* d_in, const int* in_sizes, int n_in,
                              void* d_out, int out_size, void* d_ws, size_t ws_size,
                              hipStream_t stream) {
  const float* x  = (const float*)d_in[0];   // [4,4096,4096]
  const float* W  = (const float*)d_in[1];   // [4096,4096]
  const float* b  = (const float*)d_in[2];   // [4096]
  const float* lA = (const float*)d_in[3];   // [16,4096]
  const float* lB = (const float*)d_in[4];   // [4096,16]
  float* out = (float*)d_out;                // [4,4096,4096] fp32

  unsigned short* xb = (unsigned short*)d_ws;
  unsigned short* Wp = (unsigned short*)((char*)d_ws + (size_t)MDIM * KDIM * 2);

  conv_x_kernel<<<2048, 256, 0, stream>>>(x, xb);
  prep_w_kernel<<<2048, 256, 0, stream>>>(W, lA, lB, Wp);

  gemm256_kernel<<<1024, 512, 0, stream>>>(xb, Wp, b, out);
}

// Round 13
// 588.545 us; speedup vs baseline: 1.0351x; 1.0351x over previous
//
#include <hip/hip_runtime.h>
#include <hip/hip_bf16.h>
#include <cstdint>

// Problem constants (fixed by the reference)
constexpr int  KDIM  = 4096;    // D_IN
constexpr int  NDIM  = 4096;    // D_OUT
constexpr long MDIM  = 16384;   // B*S
constexpr int  RANK_ = 16;
constexpr float SCALE_ = 2.0f;  // alpha/rank

constexpr int BK = 64;
constexpr int NT = KDIM / BK;   // 64 K-tiles

using bf16x8 = __attribute__((ext_vector_type(8))) short;
using f32x4  = __attribute__((ext_vector_type(4))) float;

__device__ __forceinline__ void gload_lds16(const void* g, void* l) {
  __builtin_amdgcn_global_load_lds(
      (const __attribute__((address_space(1))) void*)g,
      (__attribute__((address_space(3))) void*)l, 16, 0, 0);
}

__device__ __forceinline__ unsigned short f2bf(float f) {
  union { float f; unsigned u; } v; v.f = f;
  unsigned r = v.u + 0x7FFFu + ((v.u >> 16) & 1u);
  return (unsigned short)(r >> 16);
}

// immediate-offset LDS fragment read (compiler folds OFF into ds_read offset:)
#define LDF(P, OFF) (*reinterpret_cast<const bf16x8*>((P) + (OFF)))

// ---------------------------------------------------------------------------
// Kernel 1 (fused prologue): block-split between
//   blocks [0,512):    Wp = bf16( W + SCALE * lora_B @ lora_A )  [NDIM][KDIM]
//   blocks [512,4096): xb = bf16(x)                              [MDIM][KDIM]
// prep_w's 100 MB + VALU hides under conv_x's 402 MB streaming; one launch.
// ---------------------------------------------------------------------------
__global__ __launch_bounds__(256) void fused_prep_kernel(
    const float* __restrict__ x,  const float* __restrict__ W,
    const float* __restrict__ lA, const float* __restrict__ lB,
    unsigned short* __restrict__ xb, unsigned short* __restrict__ Wp) {
  if (blockIdx.x < 512) {
    // ---- W' path: 512 blocks grid-stride over NDIM*KDIM/8 vec8 groups
    const long totW = (long)NDIM * KDIM / 8;
    for (long t = blockIdx.x * 256L + threadIdx.x; t < totW; t += 512L * 256) {
      const int o  = (int)(t / (KDIM / 8));
      const int d8 = (int)(t % (KDIM / 8)) * 8;
      const float4* w4 = reinterpret_cast<const float4*>(W + (size_t)o * KDIM + d8);
      float4 w0 = w4[0], w1 = w4[1];
      float acc[8] = {w0.x, w0.y, w0.z, w0.w, w1.x, w1.y, w1.z, w1.w};
#pragma unroll
      for (int r = 0; r < RANK_; ++r) {
        const float br = SCALE_ * lB[o * RANK_ + r];
        const float4* a4 = reinterpret_cast<const float4*>(lA + (size_t)r * KDIM + d8);
        float4 a0 = a4[0], a1 = a4[1];
        acc[0] += br * a0.x; acc[1] += br * a0.y; acc[2] += br * a0.z; acc[3] += br * a0.w;
        acc[4] += br * a1.x; acc[5] += br * a1.y; acc[6] += br * a1.z; acc[7] += br * a1.w;
      }
      uint4 o4;
      o4.x = (unsigned)f2bf(acc[0]) | ((unsigned)f2bf(acc[1]) << 16);
      o4.y = (unsigned)f2bf(acc[2]) | ((unsigned)f2bf(acc[3]) << 16);
      o4.z = (unsigned)f2bf(acc[4]) | ((unsigned)f2bf(acc[5]) << 16);
      o4.w = (unsigned)f2bf(acc[6]) | ((unsigned)f2bf(acc[7]) << 16);
      *reinterpret_cast<uint4*>(Wp + t * 8) = o4;
    }
  } else {
    // ---- x path: 3584 blocks grid-stride over MDIM*KDIM/8 vec8 groups
    const long totX = MDIM * KDIM / 8;
    for (long t = (blockIdx.x - 512) * 256L + threadIdx.x; t < totX;
         t += 3584L * 256) {
      const float4* p = reinterpret_cast<const float4*>(x + t * 8);
      float4 a = p[0], b = p[1];
      uint4 o4;
      o4.x = (unsigned)f2bf(a.x) | ((unsigned)f2bf(a.y) << 16);
      o4.y = (unsigned)f2bf(a.z) | ((unsigned)f2bf(a.w) << 16);
      o4.z = (unsigned)f2bf(b.x) | ((unsigned)f2bf(b.y) << 16);
      o4.w = (unsigned)f2bf(b.z) | ((unsigned)f2bf(b.w) << 16);
      *reinterpret_cast<uint4*>(xb + t * 8) = o4;
    }
  }
}

// ---------------------------------------------------------------------------
// Kernel 2: GEMM — byte-identical to R12 (the measured best: 466 us,
//   MfmaUtil 54.5, 0 conflicts). Structure summary:
//   256x256 tile, 16x16x32 MFMA, 4 phases/K-tile, phase-ahead register loads,
//   early-issue staging (A(t+1)@P1, B(t+2)@P3), counted vmcnt(4)@P4,
//   st_16x32-family LDS swizzle (verified 0-conflict), imm-offset ds_reads,
//   XCD-bijective block swizzle, swapped-operand dwordx4 epilogue.
// ---------------------------------------------------------------------------
__global__ __launch_bounds__(512, 2) void gemm256_kernel(
    const unsigned short* __restrict__ A,   // [MDIM][KDIM] bf16 bits (x)
    const unsigned short* __restrict__ Bm,  // [NDIM][KDIM] bf16 bits (W')
    const float* __restrict__ bias,
    float* __restrict__ C) {
  __shared__ __align__(16) unsigned char lds[131072];

  const int tid  = threadIdx.x;
  const int wave = tid >> 6, lane = tid & 63;
  const int wm = wave >> 2, wn = wave & 3;       // 2 x 4 wave grid
  const int r16 = lane & 15, hi = lane >> 4;
  const int swz5 = ((r16 >> 3) & 1) << 5;        // verified-0-conflict swizzle
  const int lrB = (wn & 1) * 64;

  // XCD-aware bijective blockIdx swizzle, R4 orientation (verified lower fetch)
  const int orig = blockIdx.x;
  const int bid  = (orig & 7) * 128 + (orig >> 3);
  const int bcol = (bid & 15) * 256;             // N-tile
  const int brow = (bid >> 4) * 256;             // M-tile

  // staging geometry (verified R2): linear LDS dest + inverse-swizzled source
  const int st_row = wave * 16 + (lane >> 2);                     // 0..127
  const int st_col = ((lane & 3) * 8) ^ (((lane >> 5) & 1) << 4); // elem [0,32)
  const unsigned short* Asrc = A  + (size_t)(brow + st_row) * KDIM + st_col;
  const unsigned short* Bsrc = Bm + (size_t)(bcol + st_row) * KDIM + st_col;

  // stage half-tile s (0=B0,1=B1,2=A0,3=A1) of K-tile tau into buffer `base`
  auto stageHalf = [&](unsigned char* base, int s, int tau) {
    const unsigned short* g = (s >= 2 ? Asrc + (size_t)(s - 2) * 128 * KDIM
                                      : Bsrc + (size_t)s * 128 * KDIM) + tau * BK;
    unsigned char* d = base + (wave << 10) + s * 16384;
    gload_lds16(g,      d);            // kk0
    gload_lds16(g + 32, d + 8192);     // kk1
  };

  // per-lane ds-read base pointers; every fragment read = base + const offset:
  //   A frag (row m*16+r16, kk):      pA + m*1024 + kk*8192      (m 0..7)
  //   B frag (row lrB+n*16+r16, kk):  pB + n*1024 + kk*8192      (n 0..3)
  const int laneoff = r16 * 64 + ((hi * 16) ^ swz5);
  const unsigned char* pA0 = lds + (2 + wm) * 16384 + laneoff;
  const unsigned char* pB0 = lds + (wn >> 1) * 16384 + lrB * 64 + laneoff;
  const unsigned char* pA1 = pA0 + 65536;
  const unsigned char* pB1 = pB0 + 65536;

  f32x4 acc[8][4];
#pragma unroll
  for (int m = 0; m < 8; ++m)
#pragma unroll
    for (int n = 0; n < 4; ++n) acc[m][n] = (f32x4){0.f, 0.f, 0.f, 0.f};

  unsigned char* const buf0 = lds;
  unsigned char* const buf1 = lds + 65536;

  // prologue: tile0 full (buf0) + tile1 B0,B1 (buf1); vmcnt(4) retires tile0
  // (8 oldest loads), leaves B(1) in flight = steady-state invariant.
  stageHalf(buf0, 0, 0); stageHalf(buf0, 1, 0);
  stageHalf(buf0, 2, 0); stageHalf(buf0, 3, 0);
  stageHalf(buf1, 0, 1); stageHalf(buf1, 1, 1);
  asm volatile("s_waitcnt vmcnt(4)" ::: "memory");
  __builtin_amdgcn_s_barrier();

  bf16x8 xlo[4][2], xhi[4][2], wlo[2][2], whi[2][2];
  // boundary pre-read for tile 0: xlo (both kk) from buf0
#pragma unroll
  for (int m = 0; m < 4; ++m) {
    xlo[m][0] = LDF(pA0, m * 1024);
    xlo[m][1] = LDF(pA0, m * 1024 + 8192);
  }

  // One K-tile. CB/NB = cur/next staging buffer; PA/PB = cur read bases;
  // PAN = next A read base; t = tile index.
#define KTILE(CB, NB, PA, PB, PAN, t)                                          \
  {                                                                            \
    /* P1: read wlo+whi(t) (8); stage A0+A1(t+1); Q0 (xlo from prev P4) */     \
    _Pragma("unroll")                                                          \
    for (int n = 0; n < 2; ++n) {                                              \
      wlo[n][0] = LDF(PB, n * 1024);                                           \
      wlo[n][1] = LDF(PB, n * 1024 + 8192);                                    \
    }                                                                          \
    _Pragma("unroll")                                                          \
    for (int n = 0; n < 2; ++n) {                                              \
      whi[n][0] = LDF(PB, (n + 2) * 1024);                                     \
      whi[n][1] = LDF(PB, (n + 2) * 1024 + 8192);                              \
    }                                                                          \
    if ((t) + 1 < NT) { stageHalf((NB), 2, (t) + 1);                           \
                        stageHalf((NB), 3, (t) + 1); }                         \
    __builtin_amdgcn_s_setprio(1);                                             \
    _Pragma("unroll")                                                          \
    for (int kk = 0; kk < 2; ++kk)                                             \
      _Pragma("unroll")                                                        \
      for (int m = 0; m < 4; ++m)                                              \
        _Pragma("unroll")                                                      \
        for (int n = 0; n < 2; ++n)                                            \
          acc[m][n] = __builtin_amdgcn_mfma_f32_16x16x32_bf16(                 \
              wlo[n][kk], xlo[m][kk], acc[m][n], 0, 0, 0);                     \
    __builtin_amdgcn_s_setprio(0);                                             \
    __builtin_amdgcn_s_barrier();                                              \
    /* P2: read xhi(t) (8); Q1 (whi read P1); bar */                           \
    _Pragma("unroll")                                                          \
    for (int m = 0; m < 4; ++m) {                                              \
      xhi[m][0] = LDF(PA, (m + 4) * 1024);                                     \
      xhi[m][1] = LDF(PA, (m + 4) * 1024 + 8192);                              \
    }                                                                          \
    __builtin_amdgcn_s_setprio(1);                                             \
    _Pragma("unroll")                                                          \
    for (int kk = 0; kk < 2; ++kk)                                             \
      _Pragma("unroll")                                                        \
      for (int m = 0; m < 4; ++m)                                              \
        _Pragma("unroll")                                                      \
        for (int n = 0; n < 2; ++n)                                            \
          acc[m][n + 2] = __builtin_amdgcn_mfma_f32_16x16x32_bf16(             \
              whi[n][kk], xlo[m][kk], acc[m][n + 2], 0, 0, 0);                 \
    __builtin_amdgcn_s_setprio(0);                                             \
    __builtin_amdgcn_s_barrier();                                              \
    /* P3: no reads; stage B0+B1(t+2) into CB; Q2 (xhi read P2); bar */        \
    if ((t) + 2 < NT) { stageHalf((CB), 0, (t) + 2);                           \
                        stageHalf((CB), 1, (t) + 2); }                         \
    __builtin_amdgcn_s_setprio(1);                                             \
    _Pragma("unroll")                                                          \
    for (int kk = 0; kk < 2; ++kk)                                             \
      _Pragma("unroll")                                                        \
      for (int m = 0; m < 4; ++m)                                              \
        _Pragma("unroll")                                                      \
        for (int n = 0; n < 2; ++n)                                            \
          acc[m + 4][n + 2] = __builtin_amdgcn_mfma_f32_16x16x32_bf16(         \
              whi[n][kk], xhi[m][kk], acc[m + 4][n + 2], 0, 0, 0);             \
    __builtin_amdgcn_s_setprio(0);                                             \
    __builtin_amdgcn_s_barrier();                                              \
    /* P4: vmcnt(4) -> all of t+1 resident (A ages 3 phases), B(t+2) in        \
       flight; bar; boundary read xlo(t+1) (8) overlaps Q3 */                  \
    if ((t) < NT - 2)       asm volatile("s_waitcnt vmcnt(4)" ::: "memory");   \
    else if ((t) == NT - 2) asm volatile("s_waitcnt vmcnt(0)" ::: "memory");   \
    __builtin_amdgcn_s_barrier();                                              \
    if ((t) + 1 < NT) {                                                        \
      _Pragma("unroll")                                                        \
      for (int m = 0; m < 4; ++m) {                                            \
        xlo[m][0] = LDF(PAN, m * 1024);                                        \
        xlo[m][1] = LDF(PAN, m * 1024 + 8192);                                 \
      }                                                                        \
    }                                                                          \
    __builtin_amdgcn_s_setprio(1);                                             \
    _Pragma("unroll")                                                          \
    for (int kk = 0; kk < 2; ++kk)                                             \
      _Pragma("unroll")                                                        \
      for (int m = 0; m < 4; ++m)                                              \
        _Pragma("unroll")                                                      \
        for (int n = 0; n < 2; ++n)                                            \
          acc[m + 4][n] = __builtin_amdgcn_mfma_f32_16x16x32_bf16(             \
              wlo[n][kk], xhi[m][kk], acc[m + 4][n], 0, 0, 0);                 \
    __builtin_amdgcn_s_setprio(0);                                             \
  }

  for (int tt = 0; tt < NT; tt += 2) {
    KTILE(buf0, buf1, pA0, pB0, pA1, tt);
    KTILE(buf1, buf0, pA1, pB1, pA0, tt + 1);
  }
#undef KTILE

  // epilogue (verified R3/R4): swapped C/D layout -> lane holds 4 consecutive
  // C columns: Crow = brow + wm*128 + m*16 + (lane&15),
  //            Ccol = bcol + wn*64 + n*16 + hi*4 + j  -> dwordx4 stores
#pragma unroll
  for (int n = 0; n < 4; ++n) {
    const int colb = bcol + wn * 64 + n * 16 + hi * 4;
    const f32x4 bv = *reinterpret_cast<const f32x4*>(&bias[colb]);
#pragma unroll
    for (int m = 0; m < 8; ++m) {
      const size_t row = (size_t)brow + wm * 128 + m * 16 + r16;
      f32x4 v = acc[m][n] + bv;
      *reinterpret_cast<f32x4*>(&C[row * NDIM + colb]) = v;
    }
  }
}

// ---------------------------------------------------------------------------
extern "C" void kernel_launch(void* const* d_in, const int* in_sizes, int n_in,
                              void* d_out, int out_size, void* d_ws, size_t ws_size,
                              hipStream_t stream) {
  const float* x  = (const float*)d_in[0];   // [4,4096,4096]
  const float* W  = (const float*)d_in[1];   // [4096,4096]
  const float* b  = (const float*)d_in[2];   // [4096]
  const float* lA = (const float*)d_in[3];   // [16,4096]
  const float* lB = (const float*)d_in[4];   // [4096,16]
  float* out = (float*)d_out;                // [4,4096,4096] fp32

  unsigned short* xb = (unsigned short*)d_ws;
  unsigned short* Wp = (unsigned short*)((char*)d_ws + (size_t)MDIM * KDIM * 2);

  fused_prep_kernel<<<4096, 256, 0, stream>>>(x, W, lA, lB, xb, Wp);
  gemm256_kernel<<<1024, 512, 0, stream>>>(xb, Wp, b, out);
}